// Round 14
// baseline (668.785 us; speedup 1.0000x reference)
//
#include <hip/hip_runtime.h>
#include <math.h>

#define NTH 256

using short8 = __attribute__((ext_vector_type(8))) short;
using f32x4  = __attribute__((ext_vector_type(4))) float;

__device__ __forceinline__ unsigned short f2bf(float x) {
    unsigned u = __float_as_uint(x);
    u += 0x7fff + ((u >> 16) & 1);          // round-to-nearest-even
    return (unsigned short)(u >> 16);
}
__device__ __forceinline__ float bf2f(unsigned short h) {
    return __uint_as_float(((unsigned)h) << 16);
}

// ---- u64-key max, one DPP level (key-only) ----
template<int CTRL>
__device__ __forceinline__ unsigned long long dppmax(unsigned long long k) {
    unsigned lo = (unsigned)k, hi = (unsigned)(k >> 32);
    unsigned plo = (unsigned)__builtin_amdgcn_update_dpp(0, (int)lo, CTRL, 0xF, 0xF, true);
    unsigned phi = (unsigned)__builtin_amdgcn_update_dpp(0, (int)hi, CTRL, 0xF, 0xF, true);
    unsigned long long p = ((unsigned long long)phi << 32) | plo;
    return p > k ? p : k;   // 0-filled lanes never win (keys strictly > 0)
}

// ============================= FPS part1 (NPC centers, spills state) =============================
template<int N, int NPOINT, int NTHR, int NPC>
__device__ __forceinline__ void fps1a_body(
    const float* __restrict__ xyz, float* __restrict__ out_xyz, int b,
    float* __restrict__ pts, float* __restrict__ ctr /*NPC*3*/,
    unsigned long long* __restrict__ wkey,
    float* __restrict__ sdist, int* __restrict__ slast)
{
    constexpr int PT = N / NTHR;
    constexpr int NW = NTHR / 64;
    const int tid  = threadIdx.x;
    const int lane = tid & 63;
    const int w    = tid >> 6;
    const float* src = xyz + (size_t)b * N * 3;

    __builtin_amdgcn_s_setprio(1);
    for (int e = tid; e < N * 3; e += NTHR) pts[e] = src[e];

    float px[PT], py[PT], pz[PT], dist[PT];
    unsigned klo[PT];
#pragma unroll
    for (int j = 0; j < PT; ++j) {
        int i = j * NTHR + tid;
        px[j] = src[i * 3 + 0]; py[j] = src[i * 3 + 1]; pz[j] = src[i * 3 + 2];
        klo[j] = ~(unsigned)i;
        dist[j] = 1e10f;
    }
    int last = 0;
    if (tid == 0) { ctr[0] = src[0]; ctr[1] = src[1]; ctr[2] = src[2]; }
    __syncthreads();

    for (int c = 1; c < NPC; ++c) {
        const float lx = pts[last * 3 + 0];
        const float ly = pts[last * 3 + 1];
        const float lz = pts[last * 3 + 2];
        unsigned long long best = 0ull;
#pragma unroll
        for (int j = 0; j < PT; ++j) {
            float dx = px[j] - lx, dy = py[j] - ly, dz = pz[j] - lz;
            float d = __fadd_rn(__fadd_rn(__fmul_rn(dx, dx), __fmul_rn(dy, dy)),
                                __fmul_rn(dz, dz));
            float nd = fminf(dist[j], d);
            dist[j] = nd;
            unsigned long long key =
                ((unsigned long long)__float_as_uint(nd) << 32) | (unsigned long long)klo[j];
            best = (key > best) ? key : best;
        }
        best = dppmax<0xB1>(best);
        best = dppmax<0x4E>(best);
        best = dppmax<0x141>(best);
        best = dppmax<0x140>(best);
        best = dppmax<0x142>(best);
        best = dppmax<0x143>(best);
        const int p = (c & 1) * NW;
        if (lane == 63) wkey[p + w] = best;
        __syncthreads();
        unsigned long long K0[NW];
#pragma unroll
        for (int v = 0; v < NW; ++v) K0[v] = wkey[p + v];
#pragma unroll
        for (int st = NW / 2; st > 0; st >>= 1)
#pragma unroll
            for (int v = 0; v < st; ++v) K0[v] = (K0[v + st] > K0[v]) ? K0[v + st] : K0[v];
        last = (int)(~(unsigned)K0[0]);
        if (tid == 0) {
            ctr[c * 3 + 0] = pts[last * 3 + 0];
            ctr[c * 3 + 1] = pts[last * 3 + 1];
            ctr[c * 3 + 2] = pts[last * 3 + 2];
        }
    }
    __syncthreads();
    {
        float* sd = sdist + (size_t)b * N;
#pragma unroll
        for (int j = 0; j < PT; ++j) sd[j * NTHR + tid] = dist[j];
        if (tid == 0) slast[b] = last;
    }
    float* dst = out_xyz + (size_t)b * NPOINT * 3;
    for (int e = tid; e < NPC * 3; e += NTHR) dst[e] = ctr[e];
    __builtin_amdgcn_s_setprio(0);
}

// ======= FPS part2: resumes state, ITERS iters, 64-chunk flushes with release flags =======
template<int N, int NTHR, int ITERS, int BASE>
__device__ __forceinline__ void fps1b_body(
    const float* __restrict__ xyz, float* __restrict__ out_xyz /*nxyz1*/, int b,
    float* __restrict__ pts, float* __restrict__ ctr /*ITERS*3*/,
    unsigned long long* __restrict__ wkey,
    const float* __restrict__ sdist, const int* __restrict__ slast,
    int* __restrict__ flags)
{
    constexpr int PT = N / NTHR;
    constexpr int NW = NTHR / 64;
    const int tid  = threadIdx.x;
    const int lane = tid & 63;
    const int w    = tid >> 6;
    const float* src = xyz + (size_t)b * N * 3;

    __builtin_amdgcn_s_setprio(1);
    for (int e = tid; e < N * 3; e += NTHR) pts[e] = src[e];

    float px[PT], py[PT], pz[PT], dist[PT];
    unsigned klo[PT];
#pragma unroll
    for (int j = 0; j < PT; ++j) {
        int i = j * NTHR + tid;
        px[j] = src[i * 3 + 0]; py[j] = src[i * 3 + 1]; pz[j] = src[i * 3 + 2];
        klo[j] = ~(unsigned)i;
    }
    {
        const float* sd = sdist + (size_t)b * N;
#pragma unroll
        for (int j = 0; j < PT; ++j) dist[j] = sd[j * NTHR + tid];
    }
    int last = slast[b];
    __syncthreads();

    for (int c = 0; c < ITERS; ++c) {
        const float lx = pts[last * 3 + 0];
        const float ly = pts[last * 3 + 1];
        const float lz = pts[last * 3 + 2];
        unsigned long long best = 0ull;
#pragma unroll
        for (int j = 0; j < PT; ++j) {
            float dx = px[j] - lx, dy = py[j] - ly, dz = pz[j] - lz;
            float d = __fadd_rn(__fadd_rn(__fmul_rn(dx, dx), __fmul_rn(dy, dy)),
                                __fmul_rn(dz, dz));
            float nd = fminf(dist[j], d);
            dist[j] = nd;
            unsigned long long key =
                ((unsigned long long)__float_as_uint(nd) << 32) | (unsigned long long)klo[j];
            best = (key > best) ? key : best;
        }
        best = dppmax<0xB1>(best);
        best = dppmax<0x4E>(best);
        best = dppmax<0x141>(best);
        best = dppmax<0x140>(best);
        best = dppmax<0x142>(best);
        best = dppmax<0x143>(best);
        const int p = (c & 1) * NW;
        if (lane == 63) wkey[p + w] = best;
        __syncthreads();
        unsigned long long K0[NW];
#pragma unroll
        for (int v = 0; v < NW; ++v) K0[v] = wkey[p + v];
#pragma unroll
        for (int st = NW / 2; st > 0; st >>= 1)
#pragma unroll
            for (int v = 0; v < st; ++v) K0[v] = (K0[v + st] > K0[v]) ? K0[v + st] : K0[v];
        last = (int)(~(unsigned)K0[0]);
        if (tid == 0) {
            ctr[c * 3 + 0] = pts[last * 3 + 0];
            ctr[c * 3 + 1] = pts[last * 3 + 1];
            ctr[c * 3 + 2] = pts[last * 3 + 2];
        }
        if ((c & 63) == 63) {
            const int q = c >> 6;
            __syncthreads();   // ctr chunk complete
            float* dst = out_xyz + ((size_t)b * 512 + BASE + q * 64) * 3;
            for (int e = tid; e < 192; e += NTHR) dst[e] = ctr[q * 192 + e];
            __syncthreads();   // stores drained before release
            if (tid == 0)
                __hip_atomic_store(&flags[b * 4 + q], 1,
                                   __ATOMIC_RELEASE, __HIP_MEMORY_SCOPE_AGENT);
        }
    }
    __builtin_amdgcn_s_setprio(0);
}

// ======== FPS2 single-wave (zero barriers in loop), chained after fps1b ========
template<int N, int NPOINT>
__device__ __forceinline__ void fps2_wave_body(
    const float* __restrict__ xyz, float* __restrict__ out_xyz, int b,
    float* __restrict__ pts, float* __restrict__ ctr)
{
    const int tid = threadIdx.x;
    const float* src = xyz + (size_t)b * N * 3;
    for (int e = tid; e < N * 3; e += NTH) pts[e] = src[e];
    __syncthreads();
    if (tid < 64) {
        __builtin_amdgcn_s_setprio(1);
        constexpr int PT = N / 64;
        const int lane = tid;
        float px[PT], py[PT], pz[PT], dist[PT];
        unsigned klo[PT];
#pragma unroll
        for (int j = 0; j < PT; ++j) {
            int i = j * 64 + lane;
            px[j] = pts[i * 3 + 0]; py[j] = pts[i * 3 + 1]; pz[j] = pts[i * 3 + 2];
            dist[j] = 1e10f;
            klo[j] = ~(unsigned)i;
        }
        int last = 0;
        if (lane == 0) { ctr[0] = pts[0]; ctr[1] = pts[1]; ctr[2] = pts[2]; }
        for (int it = 1; it < NPOINT; ++it) {
            const float lx = pts[last * 3 + 0];
            const float ly = pts[last * 3 + 1];
            const float lz = pts[last * 3 + 2];
            unsigned long long best = 0ull;
#pragma unroll
            for (int j = 0; j < PT; ++j) {
                float dx = px[j] - lx, dy = py[j] - ly, dz = pz[j] - lz;
                float d = __fadd_rn(__fadd_rn(__fmul_rn(dx, dx), __fmul_rn(dy, dy)),
                                    __fmul_rn(dz, dz));
                float nd = fminf(dist[j], d);
                dist[j] = nd;
                unsigned long long key =
                    ((unsigned long long)__float_as_uint(nd) << 32) | (unsigned long long)klo[j];
                best = (key > best) ? key : best;
            }
            best = dppmax<0xB1>(best);
            best = dppmax<0x4E>(best);
            best = dppmax<0x141>(best);
            best = dppmax<0x140>(best);
            best = dppmax<0x142>(best);
            best = dppmax<0x143>(best);
            unsigned long long g = __shfl(best, 63);
            last = (int)(~(unsigned)g);
            if (lane == 0) {
                ctr[it * 3 + 0] = pts[last * 3 + 0];
                ctr[it * 3 + 1] = pts[last * 3 + 1];
                ctr[it * 3 + 2] = pts[last * 3 + 2];
            }
        }
        __builtin_amdgcn_s_setprio(0);
    }
    __syncthreads();
    float* dst = out_xyz + (size_t)b * NPOINT * 3;
    for (int e = tid; e < NPOINT * 3; e += NTH) dst[e] = ctr[e];
}

// ===================== Weight prep (grid-strided, unchanged) =====================
#define PREP_TOT 813056
__device__ __forceinline__ void prep_body(
    int gid, int stride,
    const float* __restrict__ w0, const float* __restrict__ w1, const float* __restrict__ w2,
    const float* __restrict__ w3, const float* __restrict__ w4, const float* __restrict__ w5,
    const float* __restrict__ w6, const float* __restrict__ w7, const float* __restrict__ w8,
    unsigned short* __restrict__ outw)
{
    const int K_[9]    = {3, 64, 64, 131, 128, 128, 259, 256, 512};
    const int N_[9]    = {64, 64, 128, 128, 128, 256, 256, 512, 1024};
    const int E_[9]    = {2048, 4096, 8192, 20480, 16384, 32768, 73728, 131072, 524288};
    const int base_[9] = {0, 4096, 12288, 28672, 69632, 102400, 167936, 315392, 577536};
    const int PCF_[9]  = {0, 0, 0, 128, 0, 0, 256, 0, 0};
    const float* W_[9] = {w0, w1, w2, w3, w4, w5, w6, w7, w8};
    for (; gid < PREP_TOT; gid += stride) {
        int i = 0, t = gid;
        while (t >= E_[i]) { t -= E_[i]; ++i; }
        const int Nn = N_[i];
        const int k8 = t / (Nn * 8);
        const int rem = t - k8 * Nn * 8;
        const int col = rem >> 3, j = rem & 7;
        const int k = k8 * 8 + j;
        float v = 0.f;
        if (k < K_[i]) {
            int ks = k;
            const int pcf = PCF_[i];
            if (pcf > 0) ks = (k < pcf) ? (k + 3) : (k - pcf);
            v = W_[i][(size_t)ks * Nn + col];
        }
        unsigned short hi = f2bf(v);
        unsigned short lo = f2bf(v - bf2f(hi));
        outw[base_[i] + t] = hi;
        outw[base_[i] + E_[i] + t] = lo;
    }
}

// ===================== split-bf16 MFMA MLP layer (kc loop unroll-2: prefetch B-frags) =====================
template<int K, int NSUB, int NOFF, int NFULL, int RTILES, int SX, int SY, bool FINAL>
__device__ __forceinline__ void mfma_layer(
    const unsigned short* __restrict__ whi, const unsigned short* __restrict__ wlo,
    const float* __restrict__ gm, const float* __restrict__ bt,
    const unsigned short* __restrict__ Xhi, const unsigned short* __restrict__ Xlo,
    unsigned short* __restrict__ Yhi, unsigned short* __restrict__ Ylo,
    float* outp, int tid)
{
    constexpr int KP  = (K + 31) & ~31;
    constexpr int KC  = KP / 32;
    constexpr int NTW = NSUB / 64;
    static_assert(NSUB % 64 == 0, "col split");
    const int w = tid >> 6, lane = tid & 63;
    const int lr = lane & 15, lg = lane >> 4;
    const int colbase = NOFF + w * (NSUB / 4);

    f32x4 acc[RTILES][NTW];
#pragma unroll
    for (int m = 0; m < RTILES; ++m)
#pragma unroll
        for (int t = 0; t < NTW; ++t) acc[m][t] = f32x4{0.f, 0.f, 0.f, 0.f};

    const unsigned short* xh0 = Xhi + lr * SX + lg * 8;
    const unsigned short* xl0 = Xlo + lr * SX + lg * 8;

#pragma unroll 2
    for (int kc = 0; kc < KC; ++kc) {
        const size_t krow = (size_t)(kc * 4 + lg) * NFULL * 8;
        short8 bh[NTW], bl[NTW];
#pragma unroll
        for (int t = 0; t < NTW; ++t) {
            const int col = colbase + t * 16 + lr;
            bh[t] = *reinterpret_cast<const short8*>(whi + krow + (size_t)col * 8);
            bl[t] = *reinterpret_cast<const short8*>(wlo + krow + (size_t)col * 8);
        }
#pragma unroll
        for (int m = 0; m < RTILES; ++m) {
            short8 ah = *reinterpret_cast<const short8*>(xh0 + m * 16 * SX + kc * 32);
            short8 al = *reinterpret_cast<const short8*>(xl0 + m * 16 * SX + kc * 32);
#pragma unroll
            for (int t = 0; t < NTW; ++t) {
                acc[m][t] = __builtin_amdgcn_mfma_f32_16x16x32_bf16(ah, bh[t], acc[m][t], 0, 0, 0);
                acc[m][t] = __builtin_amdgcn_mfma_f32_16x16x32_bf16(ah, bl[t], acc[m][t], 0, 0, 0);
                acc[m][t] = __builtin_amdgcn_mfma_f32_16x16x32_bf16(al, bh[t], acc[m][t], 0, 0, 0);
            }
        }
    }
#pragma unroll
    for (int t = 0; t < NTW; ++t) {
        const int col = colbase + t * 16 + lr;
        const float gv = gm[col], bv = bt[col];
        if constexpr (FINAL) {
            float mx = 0.f;
#pragma unroll
            for (int m = 0; m < RTILES; ++m)
#pragma unroll
                for (int r = 0; r < 4; ++r)
                    mx = fmaxf(mx, fmaxf(fmaf(acc[m][t][r], gv, bv), 0.f));
            mx = fmaxf(mx, __shfl_xor(mx, 16));
            mx = fmaxf(mx, __shfl_xor(mx, 32));
            if (lg == 0)
                atomicMax(reinterpret_cast<int*>(outp) + col, __float_as_int(mx));
        } else {
#pragma unroll
            for (int m = 0; m < RTILES; ++m)
#pragma unroll
                for (int r = 0; r < 4; ++r) {
                    float v = fmaxf(fmaf(acc[m][t][r], gv, bv), 0.f);
                    unsigned short hi = f2bf(v);
                    unsigned short lo = f2bf(v - bf2f(hi));
                    const int row = m * 16 + lg * 4 + r;
                    Yhi[row * SY + col] = hi;
                    Ylo[row * SY + col] = lo;
                }
        }
    }
}

// ===================== SA body with FUSED ball query (unchanged logic) =====================
template<int CF, int C0, int C1, int C2, int R>
struct SaCfg {
    static constexpr int CIN = 3 + CF;
    static constexpr int KP0 = (CIN + 31) & ~31;
    static constexpr int SX = KP0 + 8, SY1 = C0 + 8, SY2 = C1 + 8;
    static constexpr int RT = R / 16;
    static constexpr int OFF_Y1 = 0;
    static constexpr int OFF_X = 2 * R * SY1;
    static constexpr int XSZ = 2 * R * SX, Y2SZ = 2 * R * SY2;
    static constexpr int TOT = OFF_X + (XSZ > Y2SZ ? XSZ : Y2SZ);
    static constexpr int BYTES = TOT * 2 + 264 * 4;
};

template<int CF, int C0, int C1, int C2, int R>
__device__ __forceinline__ void sa_body(
    unsigned short* __restrict__ sm, int* __restrict__ bqm,
    int b, int cs, int S, int half,
    const float* __restrict__ src_xyz, const float* __restrict__ src_feat,
    const float* __restrict__ centers,
    const unsigned short* __restrict__ w0h, const unsigned short* __restrict__ w0l,
    const unsigned short* __restrict__ w1h, const unsigned short* __restrict__ w1l,
    const unsigned short* __restrict__ w2h, const unsigned short* __restrict__ w2l,
    const float* __restrict__ g0, const float* __restrict__ b0,
    const float* __restrict__ g1, const float* __restrict__ b1,
    const float* __restrict__ g2, const float* __restrict__ b2,
    float* __restrict__ out_feat, int N, float r2)
{
    using C = SaCfg<CF, C0, C1, C2, R>;
    constexpr int TPR = NTH / R;
    const int tid  = threadIdx.x;
    const int lane = tid & 63;
    const int w    = tid >> 6;
    const int bs   = b * S + cs;

    const float cx = centers[(size_t)bs * 3 + 0];
    const float cy = centers[(size_t)bs * 3 + 1];
    const float cz = centers[(size_t)bs * 3 + 2];

    {
        const int seg = N >> 2;
        const float* px = src_xyz + (size_t)b * N * 3;
        int count = 0, first = -1;
        const int bend = (w + 1) * seg;
        for (int base = w * seg; base < bend && count < 64; base += 64) {
            int i = base + lane;
            float dx = px[i * 3 + 0] - cx, dy = px[i * 3 + 1] - cy, dz = px[i * 3 + 2] - cz;
            float d2 = __fadd_rn(__fadd_rn(__fmul_rn(dx, dx), __fmul_rn(dy, dy)),
                                 __fmul_rn(dz, dz));
            bool inb = d2 < r2;
            unsigned long long m = __ballot(inb);
            if (first < 0 && m) first = base + (__ffsll(m) - 1);
            if (inb) {
                int pos = count + (int)__popcll(m & ((1ull << lane) - 1ull));
                if (pos < 64) bqm[w * 64 + pos] = i;
            }
            count += (int)__popcll(m);
        }
        if (lane == 0) {
            bqm[256 + w] = count > 64 ? 64 : count;
            bqm[260 + w] = first;
        }
    }
    __syncthreads();

    unsigned short* Xhi = sm + C::OFF_X;    unsigned short* Xlo = Xhi + R * C::SX;
    unsigned short* Y1h = sm + C::OFF_Y1;   unsigned short* Y1l = Y1h + R * C::SY1;
    unsigned short* Y2h = sm + C::OFF_X;    unsigned short* Y2l = Y2h + R * C::SY2;

    {
        const int r = tid / TPR, s = tid % TPR;
        int pid;
        {
            const int cA = bqm[256 + 0], cB = bqm[256 + 1], cC = bqm[256 + 2], cD = bqm[256 + 3];
            const int tot = cA + cB + cC + cD;
            int t = half * R + r;
            if (t < tot) {
                int ww = 0;
                if (t >= cA) { t -= cA; ww = 1;
                    if (t >= cB) { t -= cB; ww = 2;
                        if (t >= cC) { t -= cC; ww = 3; } } }
                pid = bqm[ww * 64 + t];
            } else {
                const int fA = bqm[260 + 0], fB = bqm[260 + 1], fC = bqm[260 + 2], fD = bqm[260 + 3];
                pid = fA >= 0 ? fA : (fB >= 0 ? fB : (fC >= 0 ? fC : (fD >= 0 ? fD : (N - 1))));
            }
        }
        unsigned short* xh = Xhi + r * C::SX;
        unsigned short* xl = Xlo + r * C::SX;
        if constexpr (CF > 0) {
            constexpr int CPT = CF / TPR;
            const float* frow = src_feat + ((size_t)b * N + pid) * CF + s * CPT;
#pragma unroll
            for (int q = 0; q < CPT / 4; ++q) {
                float4 v4 = *reinterpret_cast<const float4*>(frow + q * 4);
                ushort4 h, l;
                h.x = f2bf(v4.x); l.x = f2bf(v4.x - bf2f(h.x));
                h.y = f2bf(v4.y); l.y = f2bf(v4.y - bf2f(h.y));
                h.z = f2bf(v4.z); l.z = f2bf(v4.z - bf2f(h.z));
                h.w = f2bf(v4.w); l.w = f2bf(v4.w - bf2f(h.w));
                *reinterpret_cast<ushort4*>(xh + s * CPT + q * 4) = h;
                *reinterpret_cast<ushort4*>(xl + s * CPT + q * 4) = l;
            }
        }
        if (s < 3) {
            float p = src_xyz[((size_t)b * N + pid) * 3 + s]
                      - (s == 0 ? cx : (s == 1 ? cy : cz));
            unsigned short hi = f2bf(p), lo = f2bf(p - bf2f(hi));
            xh[CF + s] = hi; xl[CF + s] = lo;
        }
        constexpr int PADPER = (C::KP0 - C::CIN + TPR - 1) / TPR;
#pragma unroll
        for (int q = 0; q < PADPER; ++q) {
            int c = C::CIN + s * PADPER + q;
            if (c < C::KP0) { xh[c] = 0; xl[c] = 0; }
        }
    }
    __syncthreads();
    mfma_layer<C::CIN, C0, 0, C0, C::RT, C::SX, C::SY1, false>(
        w0h, w0l, g0, b0, Xhi, Xlo, Y1h, Y1l, nullptr, tid);
    __syncthreads();
    mfma_layer<C0, C1, 0, C1, C::RT, C::SY1, C::SY2, false>(
        w1h, w1l, g1, b1, Y1h, Y1l, Y2h, Y2l, nullptr, tid);
    __syncthreads();
    mfma_layer<C1, C2, 0, C2, C::RT, C::SY2, 0, true>(
        w2h, w2l, g2, b2, Y2h, Y2l, nullptr, nullptr,
        out_feat + (size_t)bs * C2, tid);
}

// ============================= Kernels =============================
// K1: FPS1 part1 (256 centers) + weight prep + zero-fill
template<int N1>
__global__ __launch_bounds__(NTH) void k_fps1a_prep(
    const float* __restrict__ pc, float* __restrict__ nxyz1,
    const float* __restrict__ w0, const float* __restrict__ w1, const float* __restrict__ w2,
    const float* __restrict__ w3, const float* __restrict__ w4, const float* __restrict__ w5,
    const float* __restrict__ w6, const float* __restrict__ w7, const float* __restrict__ w8,
    unsigned short* __restrict__ outw,
    float* __restrict__ sdist, int* __restrict__ slast,
    float4* __restrict__ z1, int n1, float4* __restrict__ z2, int n2,
    float4* __restrict__ z3, int n3, float4* __restrict__ z4, int n4,
    int nfps, int nprep)
{
    __shared__ float pts[N1 * 3];
    __shared__ float ctr[256 * 3];
    __shared__ unsigned long long wkey[2 * (NTH / 64)];
    if ((int)blockIdx.x < nfps) {
        fps1a_body<N1, 512, NTH, 256>(pc, nxyz1, blockIdx.x, pts, ctr, wkey, sdist, slast);
    } else if ((int)blockIdx.x < nfps + nprep) {
        prep_body((blockIdx.x - nfps) * NTH + threadIdx.x, nprep * NTH,
                  w0, w1, w2, w3, w4, w5, w6, w7, w8, outw);
    } else {
        const int zid = (blockIdx.x - nfps - nprep) * NTH + threadIdx.x;
        const int zs  = (gridDim.x - nfps - nprep) * NTH;
        const float4 zv = make_float4(0.f, 0.f, 0.f, 0.f);
        for (int i = zid; i < n4; i += zs) z4[i] = zv;   // flags first
        for (int i = zid; i < n1; i += zs) z1[i] = zv;
        for (int i = zid; i < n2; i += zs) z2[i] = zv;
        for (int i = zid; i < n3; i += zs) z3[i] = zv;
    }
}

// K2: [FPS1 part2 (256 iters, chunk flags) -> FPS2] (blocks 0..31) || SA1 ALL
__global__ __launch_bounds__(NTH) void k_fps1b2_sa1(
    const float* __restrict__ pc, float* __restrict__ nxyz1, float* __restrict__ nxyz2,
    const float* __restrict__ sdist, const int* __restrict__ slast,
    int* __restrict__ flags,
    const unsigned short* __restrict__ w0h, const unsigned short* __restrict__ w0l,
    const unsigned short* __restrict__ w1h, const unsigned short* __restrict__ w1l,
    const unsigned short* __restrict__ w2h, const unsigned short* __restrict__ w2l,
    const float* __restrict__ g0, const float* __restrict__ b0,
    const float* __restrict__ g1, const float* __restrict__ b1,
    const float* __restrict__ g2, const float* __restrict__ b2,
    float* __restrict__ feat1, float r2)
{
    constexpr int FPSB = 4096 * 3 * 4 + 256 * 3 * 4 + 2 * (NTH / 64) * 8;
    constexpr int SAB  = SaCfg<0, 64, 64, 128, 64>::BYTES;
    constexpr int BYTES = FPSB > SAB ? FPSB : SAB;
    __shared__ __align__(16) char raw[BYTES];
    if ((int)blockIdx.x < 32) {
        const int b = blockIdx.x;
        {
            float* pts = (float*)raw;
            float* ctr = (float*)(raw + 4096 * 3 * 4);
            unsigned long long* wkey = (unsigned long long*)(raw + 4096 * 3 * 4 + 256 * 3 * 4);
            fps1b_body<4096, NTH, 256, 256>(pc, nxyz1, b, pts, ctr, wkey, sdist, slast, flags);
        }
        __syncthreads();
        {
            float* pts = (float*)raw;
            float* ctr = (float*)(raw + 512 * 3 * 4);
            fps2_wave_body<512, 128>(nxyz1, nxyz2, b, pts, ctr);
        }
    } else {
        // grid ordered by 64-center group: groups 0..3 (cs<256) dispatch first, no wait
        const int blk = blockIdx.x - 32;
        const int g = blk / (32 * 64);
        const int o = blk % (32 * 64);
        const int b = o >> 6;
        const int cs = g * 64 + (o & 63);
        if (cs >= 256) {
            if (threadIdx.x == 0) {
                while (__hip_atomic_load(&flags[b * 4 + ((cs >> 6) - 4)],
                                         __ATOMIC_ACQUIRE, __HIP_MEMORY_SCOPE_AGENT) == 0)
                    __builtin_amdgcn_s_sleep(16);
            }
            __syncthreads();
        }
        unsigned short* sm = (unsigned short*)raw;
        int* bqm = (int*)(raw + SaCfg<0, 64, 64, 128, 64>::TOT * 2);
        sa_body<0, 64, 64, 128, 64>(sm, bqm, b, cs, 512, 0,
                                    pc, nullptr, nxyz1,
                                    w0h, w0l, w1h, w1l, w2h, w2l,
                                    g0, b0, g1, b1, g2, b2, feat1, 4096, r2);
    }
}

// K3: SA2 with R=64 (one block per center, bq once, 4 row-tiles)
__global__ __launch_bounds__(NTH) void k_sa2(
    const float* __restrict__ nxyz1, const float* __restrict__ feat1,
    const float* __restrict__ nxyz2,
    const unsigned short* __restrict__ w0h, const unsigned short* __restrict__ w0l,
    const unsigned short* __restrict__ w1h, const unsigned short* __restrict__ w1l,
    const unsigned short* __restrict__ w2h, const unsigned short* __restrict__ w2l,
    const float* __restrict__ g0, const float* __restrict__ b0,
    const float* __restrict__ g1, const float* __restrict__ b1,
    const float* __restrict__ g2, const float* __restrict__ b2,
    float* __restrict__ feat2, float r2)
{
    using C = SaCfg<128, 128, 128, 256, 64>;
    __shared__ __align__(16) char raw[C::BYTES];
    const int b = blockIdx.x >> 7, cs = blockIdx.x & 127;
    unsigned short* sm = (unsigned short*)raw;
    int* bqm = (int*)(raw + C::TOT * 2);
    sa_body<128, 128, 128, 256, 64>(sm, bqm, b, cs, 128, 0,
                                    nxyz1, feat1, nxyz2,
                                    w0h, w0l, w1h, w1l, w2h, w2l,
                                    g0, b0, g1, b1, g2, b2, feat2, 512, r2);
}

// ===================== Head (unchanged) =====================
template<int CF, int C0, int C1, int C2>
__global__ __launch_bounds__(NTH) void head_mfma(
    const float* __restrict__ xyz, const float* __restrict__ feat,
    const unsigned short* __restrict__ w0h, const unsigned short* __restrict__ w0l,
    const unsigned short* __restrict__ w1h, const unsigned short* __restrict__ w1l,
    const unsigned short* __restrict__ w2h, const unsigned short* __restrict__ w2l,
    const float* __restrict__ g0, const float* __restrict__ b0,
    const float* __restrict__ g1, const float* __restrict__ b1,
    const float* __restrict__ g2, const float* __restrict__ b2,
    float* __restrict__ out, int Np)
{
    constexpr int R = 16;
    constexpr int CIN = 3 + CF;
    constexpr int KP0 = (CIN + 31) & ~31;
    constexpr int SX = KP0 + 8, SY1 = C0 + 8, SY2 = C1 + 8;
    constexpr int OFF_Y1 = 0;
    constexpr int OFF_X  = 2 * R * SY1;
    constexpr int XSZ = 2 * R * SX, Y2SZ = 2 * R * SY2;
    constexpr int TOT = OFF_X + (XSZ > Y2SZ ? XSZ : Y2SZ);
    __shared__ __align__(16) unsigned short sm[TOT];
    constexpr int TPR = NTH / R;

    const int tid = threadIdx.x;
    const int chunks = Np / R;
    const int b  = blockIdx.x / chunks;
    const int r0 = (blockIdx.x % chunks) * R;

    unsigned short* Xhi = sm + OFF_X;   unsigned short* Xlo = Xhi + R * SX;
    unsigned short* Y1h = sm + OFF_Y1;  unsigned short* Y1l = Y1h + R * SY1;
    unsigned short* Y2h = sm + OFF_X;   unsigned short* Y2l = Y2h + R * SY2;

    {
        const int r = tid / TPR, s = tid % TPR;
        const int row = r0 + r;
        unsigned short* xh = Xhi + r * SX;
        unsigned short* xl = Xlo + r * SX;
        constexpr int CPT = CF / TPR;
        const float* frow = feat + ((size_t)b * Np + row) * CF + s * CPT;
#pragma unroll
        for (int q = 0; q < CPT / 4; ++q) {
            float4 v4 = *reinterpret_cast<const float4*>(frow + q * 4);
            ushort4 h, l;
            h.x = f2bf(v4.x); l.x = f2bf(v4.x - bf2f(h.x));
            h.y = f2bf(v4.y); l.y = f2bf(v4.y - bf2f(h.y));
            h.z = f2bf(v4.z); l.z = f2bf(v4.z - bf2f(h.z));
            h.w = f2bf(v4.w); l.w = f2bf(v4.w - bf2f(h.w));
            *reinterpret_cast<ushort4*>(xh + s * CPT + q * 4) = h;
            *reinterpret_cast<ushort4*>(xl + s * CPT + q * 4) = l;
        }
        if (s < 3) {
            float p = xyz[((size_t)b * Np + row) * 3 + s];
            unsigned short hi = f2bf(p), lo = f2bf(p - bf2f(hi));
            xh[CF + s] = hi; xl[CF + s] = lo;
        }
        constexpr int PADPER = (KP0 - CIN + TPR - 1) / TPR;
#pragma unroll
        for (int q = 0; q < PADPER; ++q) {
            int c = CIN + s * PADPER + q;
            if (c < KP0) { xh[c] = 0; xl[c] = 0; }
        }
    }
    __syncthreads();
    mfma_layer<CIN, C0, 0, C0, 1, SX, SY1, false>(w0h, w0l, g0, b0, Xhi, Xlo, Y1h, Y1l, nullptr, tid);
    __syncthreads();
    mfma_layer<C0, C1, 0, C1, 1, SY1, SY2, false>(w1h, w1l, g1, b1, Y1h, Y1l, Y2h, Y2l, nullptr, tid);
    __syncthreads();
    float* op = out + (size_t)b * C2;
    mfma_layer<C1, C2 / 2, 0,      C2, 1, SY2, 0, true>(w2h, w2l, g2, b2, Y2h, Y2l, nullptr, nullptr, op, tid);
    mfma_layer<C1, C2 / 2, C2 / 2, C2, 1, SY2, 0, true>(w2h, w2l, g2, b2, Y2h, Y2l, nullptr, nullptr, op, tid);
}

// ============================== launch ==============================
extern "C" void kernel_launch(void* const* d_in, const int* in_sizes, int n_in,
                              void* d_out, int out_size, void* d_ws, size_t ws_size,
                              hipStream_t stream)
{
    (void)in_sizes; (void)n_in; (void)ws_size;
    const int B = 32;
    const float* pc = (const float*)d_in[0];
    const float* W[27];
    for (int i = 0; i < 27; ++i) W[i] = (const float*)d_in[1 + i];
    float* out = (float*)d_out;

    char* ws = (char*)d_ws;
    size_t off = 0;
    auto take = [&](size_t bytes) {
        void* p = ws + off;
        off += (bytes + 255) & ~(size_t)255;
        return p;
    };
    float* nxyz1 = (float*)take((size_t)B * 512 * 3 * 4);
    float* feat1 = (float*)take((size_t)B * 512 * 128 * 4);
    float* nxyz2 = (float*)take((size_t)B * 128 * 3 * 4);
    float* feat2 = (float*)take((size_t)B * 128 * 256 * 4);
    unsigned short* wf = (unsigned short*)take((size_t)1626112 * 2);
    float* sdist = (float*)take((size_t)B * 4096 * 4);
    int*   slast = (int*)take((size_t)B * 4);
    int*   flags = (int*)take((size_t)B * 4 * 4);

    const int E_[9]    = {2048, 4096, 8192, 20480, 16384, 32768, 73728, 131072, 524288};
    const int base_[9] = {0, 4096, 12288, 28672, 69632, 102400, 167936, 315392, 577536};
    const unsigned short* wh[9]; const unsigned short* wl[9];
    for (int i = 0; i < 9; ++i) { wh[i] = wf + base_[i]; wl[i] = wf + base_[i] + E_[i]; }

    const float r2_1 = (float)(0.2 * 0.2);
    const float r2_2 = (float)(0.4 * 0.4);

    // K1: FPS1 part1 (256) + weight prep + zero-fill
    k_fps1a_prep<4096><<<32 + 512 + 64, NTH, 0, stream>>>(
        pc, nxyz1,
        W[0], W[3], W[6], W[9], W[12], W[15], W[18], W[21], W[24],
        wf, sdist, slast,
        (float4*)feat1, B * 512 * 128 / 4,
        (float4*)feat2, B * 128 * 256 / 4,
        (float4*)out,   out_size / 4,
        (float4*)flags, B * 4 * 4 / 16,
        32, 512);

    // K2: [FPS1 part2 (256) -> FPS2] || SA1 all
    k_fps1b2_sa1<<<32 + B * 512, NTH, 0, stream>>>(
        pc, nxyz1, nxyz2, sdist, slast, flags,
        wh[0], wl[0], wh[1], wl[1], wh[2], wl[2],
        W[1], W[2], W[4], W[5], W[7], W[8],
        feat1, r2_1);

    // K3: SA2 (R=64)
    k_sa2<<<B * 128, NTH, 0, stream>>>(
        nxyz1, feat1, nxyz2,
        wh[3], wl[3], wh[4], wl[4], wh[5], wl[5],
        W[10], W[11], W[13], W[14], W[16], W[17],
        feat2, r2_2);

    // K4: head
    head_mfma<256, 256, 512, 1024><<<B * 8, NTH, 0, stream>>>(
        nxyz2, feat2,
        wh[6], wl[6], wh[7], wl[7], wh[8], wl[8],
        W[19], W[20], W[22], W[23], W[25], W[26],
        out, 128);
}

// Round 15
// 597.181 us; speedup vs baseline: 1.1199x; 1.1199x over previous
//
#include <hip/hip_runtime.h>
#include <math.h>

#define NTH 256

using short8 = __attribute__((ext_vector_type(8))) short;
using f32x4  = __attribute__((ext_vector_type(4))) float;

__device__ __forceinline__ unsigned short f2bf(float x) {
    unsigned u = __float_as_uint(x);
    u += 0x7fff + ((u >> 16) & 1);          // round-to-nearest-even
    return (unsigned short)(u >> 16);
}
__device__ __forceinline__ float bf2f(unsigned short h) {
    return __uint_as_float(((unsigned)h) << 16);
}

// ---- u64-key max, one DPP level (key-only) ----
template<int CTRL>
__device__ __forceinline__ unsigned long long dppmax(unsigned long long k) {
    unsigned lo = (unsigned)k, hi = (unsigned)(k >> 32);
    unsigned plo = (unsigned)__builtin_amdgcn_update_dpp(0, (int)lo, CTRL, 0xF, 0xF, true);
    unsigned phi = (unsigned)__builtin_amdgcn_update_dpp(0, (int)hi, CTRL, 0xF, 0xF, true);
    unsigned long long p = ((unsigned long long)phi << 32) | plo;
    return p > k ? p : k;   // 0-filled lanes never win (keys strictly > 0)
}

// ============================= FPS part1 (NPC centers, spills state) =============================
template<int N, int NPOINT, int NTHR, int NPC>
__device__ __forceinline__ void fps1a_body(
    const float* __restrict__ xyz, float* __restrict__ out_xyz, int b,
    float* __restrict__ pts, float* __restrict__ ctr /*NPC*3*/,
    unsigned long long* __restrict__ wkey,
    float* __restrict__ sdist, int* __restrict__ slast)
{
    constexpr int PT = N / NTHR;
    constexpr int NW = NTHR / 64;
    const int tid  = threadIdx.x;
    const int lane = tid & 63;
    const int w    = tid >> 6;
    const float* src = xyz + (size_t)b * N * 3;

    __builtin_amdgcn_s_setprio(1);
    for (int e = tid; e < N * 3; e += NTHR) pts[e] = src[e];

    float px[PT], py[PT], pz[PT], dist[PT];
    unsigned klo[PT];
#pragma unroll
    for (int j = 0; j < PT; ++j) {
        int i = j * NTHR + tid;
        px[j] = src[i * 3 + 0]; py[j] = src[i * 3 + 1]; pz[j] = src[i * 3 + 2];
        klo[j] = ~(unsigned)i;
        dist[j] = 1e10f;
    }
    int last = 0;
    if (tid == 0) { ctr[0] = src[0]; ctr[1] = src[1]; ctr[2] = src[2]; }
    __syncthreads();

    for (int c = 1; c < NPC; ++c) {
        const float lx = pts[last * 3 + 0];
        const float ly = pts[last * 3 + 1];
        const float lz = pts[last * 3 + 2];
        unsigned long long best = 0ull;
#pragma unroll
        for (int j = 0; j < PT; ++j) {
            float dx = px[j] - lx, dy = py[j] - ly, dz = pz[j] - lz;
            float d = __fadd_rn(__fadd_rn(__fmul_rn(dx, dx), __fmul_rn(dy, dy)),
                                __fmul_rn(dz, dz));
            float nd = fminf(dist[j], d);
            dist[j] = nd;
            unsigned long long key =
                ((unsigned long long)__float_as_uint(nd) << 32) | (unsigned long long)klo[j];
            best = (key > best) ? key : best;
        }
        best = dppmax<0xB1>(best);
        best = dppmax<0x4E>(best);
        best = dppmax<0x141>(best);
        best = dppmax<0x140>(best);
        best = dppmax<0x142>(best);
        best = dppmax<0x143>(best);
        const int p = (c & 1) * NW;
        if (lane == 63) wkey[p + w] = best;
        __syncthreads();
        unsigned long long K0[NW];
#pragma unroll
        for (int v = 0; v < NW; ++v) K0[v] = wkey[p + v];
#pragma unroll
        for (int st = NW / 2; st > 0; st >>= 1)
#pragma unroll
            for (int v = 0; v < st; ++v) K0[v] = (K0[v + st] > K0[v]) ? K0[v + st] : K0[v];
        last = (int)(~(unsigned)K0[0]);
        if (tid == 0) {
            ctr[c * 3 + 0] = pts[last * 3 + 0];
            ctr[c * 3 + 1] = pts[last * 3 + 1];
            ctr[c * 3 + 2] = pts[last * 3 + 2];
        }
    }
    __syncthreads();
    {
        float* sd = sdist + (size_t)b * N;
#pragma unroll
        for (int j = 0; j < PT; ++j) sd[j * NTHR + tid] = dist[j];
        if (tid == 0) slast[b] = last;
    }
    float* dst = out_xyz + (size_t)b * NPOINT * 3;
    for (int e = tid; e < NPC * 3; e += NTHR) dst[e] = ctr[e];
    __builtin_amdgcn_s_setprio(0);
}

// ======= FPS part2: resumes state, ITERS iters, 32-chunk flushes with release flags =======
template<int N, int NTHR, int ITERS, int BASE>
__device__ __forceinline__ void fps1b_body(
    const float* __restrict__ xyz, float* __restrict__ out_xyz /*nxyz1*/, int b,
    float* __restrict__ pts, float* __restrict__ ctr /*ITERS*3*/,
    unsigned long long* __restrict__ wkey,
    const float* __restrict__ sdist, const int* __restrict__ slast,
    int* __restrict__ flags)
{
    constexpr int PT = N / NTHR;
    constexpr int NW = NTHR / 64;
    const int tid  = threadIdx.x;
    const int lane = tid & 63;
    const int w    = tid >> 6;
    const float* src = xyz + (size_t)b * N * 3;

    __builtin_amdgcn_s_setprio(1);
    for (int e = tid; e < N * 3; e += NTHR) pts[e] = src[e];

    float px[PT], py[PT], pz[PT], dist[PT];
    unsigned klo[PT];
#pragma unroll
    for (int j = 0; j < PT; ++j) {
        int i = j * NTHR + tid;
        px[j] = src[i * 3 + 0]; py[j] = src[i * 3 + 1]; pz[j] = src[i * 3 + 2];
        klo[j] = ~(unsigned)i;
    }
    {
        const float* sd = sdist + (size_t)b * N;
#pragma unroll
        for (int j = 0; j < PT; ++j) dist[j] = sd[j * NTHR + tid];
    }
    int last = slast[b];
    __syncthreads();

    for (int c = 0; c < ITERS; ++c) {
        const float lx = pts[last * 3 + 0];
        const float ly = pts[last * 3 + 1];
        const float lz = pts[last * 3 + 2];
        unsigned long long best = 0ull;
#pragma unroll
        for (int j = 0; j < PT; ++j) {
            float dx = px[j] - lx, dy = py[j] - ly, dz = pz[j] - lz;
            float d = __fadd_rn(__fadd_rn(__fmul_rn(dx, dx), __fmul_rn(dy, dy)),
                                __fmul_rn(dz, dz));
            float nd = fminf(dist[j], d);
            dist[j] = nd;
            unsigned long long key =
                ((unsigned long long)__float_as_uint(nd) << 32) | (unsigned long long)klo[j];
            best = (key > best) ? key : best;
        }
        best = dppmax<0xB1>(best);
        best = dppmax<0x4E>(best);
        best = dppmax<0x141>(best);
        best = dppmax<0x140>(best);
        best = dppmax<0x142>(best);
        best = dppmax<0x143>(best);
        const int p = (c & 1) * NW;
        if (lane == 63) wkey[p + w] = best;
        __syncthreads();
        unsigned long long K0[NW];
#pragma unroll
        for (int v = 0; v < NW; ++v) K0[v] = wkey[p + v];
#pragma unroll
        for (int st = NW / 2; st > 0; st >>= 1)
#pragma unroll
            for (int v = 0; v < st; ++v) K0[v] = (K0[v + st] > K0[v]) ? K0[v + st] : K0[v];
        last = (int)(~(unsigned)K0[0]);
        if (tid == 0) {
            ctr[c * 3 + 0] = pts[last * 3 + 0];
            ctr[c * 3 + 1] = pts[last * 3 + 1];
            ctr[c * 3 + 2] = pts[last * 3 + 2];
        }
        if ((c & 31) == 31) {
            const int q = c >> 5;                  // 32-center chunk index (0..7)
            __syncthreads();   // ctr chunk complete
            float* dst = out_xyz + ((size_t)b * 512 + BASE + q * 32) * 3;
            for (int e = tid; e < 96; e += NTHR) dst[e] = ctr[q * 96 + e];
            __syncthreads();   // stores drained before release
            if (tid == 0)
                __hip_atomic_store(&flags[b * 8 + q], 1,
                                   __ATOMIC_RELEASE, __HIP_MEMORY_SCOPE_AGENT);
        }
    }
    __builtin_amdgcn_s_setprio(0);
}

// ======== FPS2 single-wave (zero barriers in loop), chained after fps1b ========
template<int N, int NPOINT>
__device__ __forceinline__ void fps2_wave_body(
    const float* __restrict__ xyz, float* __restrict__ out_xyz, int b,
    float* __restrict__ pts, float* __restrict__ ctr)
{
    const int tid = threadIdx.x;
    const float* src = xyz + (size_t)b * N * 3;
    for (int e = tid; e < N * 3; e += NTH) pts[e] = src[e];
    __syncthreads();
    if (tid < 64) {
        __builtin_amdgcn_s_setprio(1);
        constexpr int PT = N / 64;
        const int lane = tid;
        float px[PT], py[PT], pz[PT], dist[PT];
        unsigned klo[PT];
#pragma unroll
        for (int j = 0; j < PT; ++j) {
            int i = j * 64 + lane;
            px[j] = pts[i * 3 + 0]; py[j] = pts[i * 3 + 1]; pz[j] = pts[i * 3 + 2];
            dist[j] = 1e10f;
            klo[j] = ~(unsigned)i;
        }
        int last = 0;
        if (lane == 0) { ctr[0] = pts[0]; ctr[1] = pts[1]; ctr[2] = pts[2]; }
        for (int it = 1; it < NPOINT; ++it) {
            const float lx = pts[last * 3 + 0];
            const float ly = pts[last * 3 + 1];
            const float lz = pts[last * 3 + 2];
            unsigned long long best = 0ull;
#pragma unroll
            for (int j = 0; j < PT; ++j) {
                float dx = px[j] - lx, dy = py[j] - ly, dz = pz[j] - lz;
                float d = __fadd_rn(__fadd_rn(__fmul_rn(dx, dx), __fmul_rn(dy, dy)),
                                    __fmul_rn(dz, dz));
                float nd = fminf(dist[j], d);
                dist[j] = nd;
                unsigned long long key =
                    ((unsigned long long)__float_as_uint(nd) << 32) | (unsigned long long)klo[j];
                best = (key > best) ? key : best;
            }
            best = dppmax<0xB1>(best);
            best = dppmax<0x4E>(best);
            best = dppmax<0x141>(best);
            best = dppmax<0x140>(best);
            best = dppmax<0x142>(best);
            best = dppmax<0x143>(best);
            unsigned long long g = __shfl(best, 63);
            last = (int)(~(unsigned)g);
            if (lane == 0) {
                ctr[it * 3 + 0] = pts[last * 3 + 0];
                ctr[it * 3 + 1] = pts[last * 3 + 1];
                ctr[it * 3 + 2] = pts[last * 3 + 2];
            }
        }
        __builtin_amdgcn_s_setprio(0);
    }
    __syncthreads();
    float* dst = out_xyz + (size_t)b * NPOINT * 3;
    for (int e = tid; e < NPOINT * 3; e += NTH) dst[e] = ctr[e];
}

// ===================== Weight prep (grid-strided, unchanged) =====================
#define PREP_TOT 813056
__device__ __forceinline__ void prep_body(
    int gid, int stride,
    const float* __restrict__ w0, const float* __restrict__ w1, const float* __restrict__ w2,
    const float* __restrict__ w3, const float* __restrict__ w4, const float* __restrict__ w5,
    const float* __restrict__ w6, const float* __restrict__ w7, const float* __restrict__ w8,
    unsigned short* __restrict__ outw)
{
    const int K_[9]    = {3, 64, 64, 131, 128, 128, 259, 256, 512};
    const int N_[9]    = {64, 64, 128, 128, 128, 256, 256, 512, 1024};
    const int E_[9]    = {2048, 4096, 8192, 20480, 16384, 32768, 73728, 131072, 524288};
    const int base_[9] = {0, 4096, 12288, 28672, 69632, 102400, 167936, 315392, 577536};
    const int PCF_[9]  = {0, 0, 0, 128, 0, 0, 256, 0, 0};
    const float* W_[9] = {w0, w1, w2, w3, w4, w5, w6, w7, w8};
    for (; gid < PREP_TOT; gid += stride) {
        int i = 0, t = gid;
        while (t >= E_[i]) { t -= E_[i]; ++i; }
        const int Nn = N_[i];
        const int k8 = t / (Nn * 8);
        const int rem = t - k8 * Nn * 8;
        const int col = rem >> 3, j = rem & 7;
        const int k = k8 * 8 + j;
        float v = 0.f;
        if (k < K_[i]) {
            int ks = k;
            const int pcf = PCF_[i];
            if (pcf > 0) ks = (k < pcf) ? (k + 3) : (k - pcf);
            v = W_[i][(size_t)ks * Nn + col];
        }
        unsigned short hi = f2bf(v);
        unsigned short lo = f2bf(v - bf2f(hi));
        outw[base_[i] + t] = hi;
        outw[base_[i] + E_[i] + t] = lo;
    }
}

// ===================== split-bf16 MFMA MLP layer (R12 version) =====================
template<int K, int NSUB, int NOFF, int NFULL, int RTILES, int SX, int SY, bool FINAL>
__device__ __forceinline__ void mfma_layer(
    const unsigned short* __restrict__ whi, const unsigned short* __restrict__ wlo,
    const float* __restrict__ gm, const float* __restrict__ bt,
    const unsigned short* __restrict__ Xhi, const unsigned short* __restrict__ Xlo,
    unsigned short* __restrict__ Yhi, unsigned short* __restrict__ Ylo,
    float* outp, int tid)
{
    constexpr int KP  = (K + 31) & ~31;
    constexpr int KC  = KP / 32;
    constexpr int NTW = NSUB / 64;
    static_assert(NSUB % 64 == 0, "col split");
    const int w = tid >> 6, lane = tid & 63;
    const int lr = lane & 15, lg = lane >> 4;
    const int colbase = NOFF + w * (NSUB / 4);

    f32x4 acc[RTILES][NTW];
#pragma unroll
    for (int m = 0; m < RTILES; ++m)
#pragma unroll
        for (int t = 0; t < NTW; ++t) acc[m][t] = f32x4{0.f, 0.f, 0.f, 0.f};

    const unsigned short* xh0 = Xhi + lr * SX + lg * 8;
    const unsigned short* xl0 = Xlo + lr * SX + lg * 8;

    for (int kc = 0; kc < KC; ++kc) {
        const size_t krow = (size_t)(kc * 4 + lg) * NFULL * 8;
        short8 bh[NTW], bl[NTW];
#pragma unroll
        for (int t = 0; t < NTW; ++t) {
            const int col = colbase + t * 16 + lr;
            bh[t] = *reinterpret_cast<const short8*>(whi + krow + (size_t)col * 8);
            bl[t] = *reinterpret_cast<const short8*>(wlo + krow + (size_t)col * 8);
        }
#pragma unroll
        for (int m = 0; m < RTILES; ++m) {
            short8 ah = *reinterpret_cast<const short8*>(xh0 + m * 16 * SX + kc * 32);
            short8 al = *reinterpret_cast<const short8*>(xl0 + m * 16 * SX + kc * 32);
#pragma unroll
            for (int t = 0; t < NTW; ++t) {
                acc[m][t] = __builtin_amdgcn_mfma_f32_16x16x32_bf16(ah, bh[t], acc[m][t], 0, 0, 0);
                acc[m][t] = __builtin_amdgcn_mfma_f32_16x16x32_bf16(ah, bl[t], acc[m][t], 0, 0, 0);
                acc[m][t] = __builtin_amdgcn_mfma_f32_16x16x32_bf16(al, bh[t], acc[m][t], 0, 0, 0);
            }
        }
    }
#pragma unroll
    for (int t = 0; t < NTW; ++t) {
        const int col = colbase + t * 16 + lr;
        const float gv = gm[col], bv = bt[col];
        if constexpr (FINAL) {
            float mx = 0.f;
#pragma unroll
            for (int m = 0; m < RTILES; ++m)
#pragma unroll
                for (int r = 0; r < 4; ++r)
                    mx = fmaxf(mx, fmaxf(fmaf(acc[m][t][r], gv, bv), 0.f));
            mx = fmaxf(mx, __shfl_xor(mx, 16));
            mx = fmaxf(mx, __shfl_xor(mx, 32));
            if (lg == 0)
                atomicMax(reinterpret_cast<int*>(outp) + col, __float_as_int(mx));
        } else {
#pragma unroll
            for (int m = 0; m < RTILES; ++m)
#pragma unroll
                for (int r = 0; r < 4; ++r) {
                    float v = fmaxf(fmaf(acc[m][t][r], gv, bv), 0.f);
                    unsigned short hi = f2bf(v);
                    unsigned short lo = f2bf(v - bf2f(hi));
                    const int row = m * 16 + lg * 4 + r;
                    Yhi[row * SY + col] = hi;
                    Ylo[row * SY + col] = lo;
                }
        }
    }
}

// ===================== SA body with FUSED ball query (unchanged) =====================
template<int CF, int C0, int C1, int C2, int R>
struct SaCfg {
    static constexpr int CIN = 3 + CF;
    static constexpr int KP0 = (CIN + 31) & ~31;
    static constexpr int SX = KP0 + 8, SY1 = C0 + 8, SY2 = C1 + 8;
    static constexpr int RT = R / 16;
    static constexpr int OFF_Y1 = 0;
    static constexpr int OFF_X = 2 * R * SY1;
    static constexpr int XSZ = 2 * R * SX, Y2SZ = 2 * R * SY2;
    static constexpr int TOT = OFF_X + (XSZ > Y2SZ ? XSZ : Y2SZ);
    static constexpr int BYTES = TOT * 2 + 264 * 4;
};

template<int CF, int C0, int C1, int C2, int R>
__device__ __forceinline__ void sa_body(
    unsigned short* __restrict__ sm, int* __restrict__ bqm,
    int b, int cs, int S, int half,
    const float* __restrict__ src_xyz, const float* __restrict__ src_feat,
    const float* __restrict__ centers,
    const unsigned short* __restrict__ w0h, const unsigned short* __restrict__ w0l,
    const unsigned short* __restrict__ w1h, const unsigned short* __restrict__ w1l,
    const unsigned short* __restrict__ w2h, const unsigned short* __restrict__ w2l,
    const float* __restrict__ g0, const float* __restrict__ b0,
    const float* __restrict__ g1, const float* __restrict__ b1,
    const float* __restrict__ g2, const float* __restrict__ b2,
    float* __restrict__ out_feat, int N, float r2)
{
    using C = SaCfg<CF, C0, C1, C2, R>;
    constexpr int TPR = NTH / R;
    const int tid  = threadIdx.x;
    const int lane = tid & 63;
    const int w    = tid >> 6;
    const int bs   = b * S + cs;

    const float cx = centers[(size_t)bs * 3 + 0];
    const float cy = centers[(size_t)bs * 3 + 1];
    const float cz = centers[(size_t)bs * 3 + 2];

    {
        const int seg = N >> 2;
        const float* px = src_xyz + (size_t)b * N * 3;
        int count = 0, first = -1;
        const int bend = (w + 1) * seg;
        for (int base = w * seg; base < bend && count < 64; base += 64) {
            int i = base + lane;
            float dx = px[i * 3 + 0] - cx, dy = px[i * 3 + 1] - cy, dz = px[i * 3 + 2] - cz;
            float d2 = __fadd_rn(__fadd_rn(__fmul_rn(dx, dx), __fmul_rn(dy, dy)),
                                 __fmul_rn(dz, dz));
            bool inb = d2 < r2;
            unsigned long long m = __ballot(inb);
            if (first < 0 && m) first = base + (__ffsll(m) - 1);
            if (inb) {
                int pos = count + (int)__popcll(m & ((1ull << lane) - 1ull));
                if (pos < 64) bqm[w * 64 + pos] = i;
            }
            count += (int)__popcll(m);
        }
        if (lane == 0) {
            bqm[256 + w] = count > 64 ? 64 : count;
            bqm[260 + w] = first;
        }
    }
    __syncthreads();

    unsigned short* Xhi = sm + C::OFF_X;    unsigned short* Xlo = Xhi + R * C::SX;
    unsigned short* Y1h = sm + C::OFF_Y1;   unsigned short* Y1l = Y1h + R * C::SY1;
    unsigned short* Y2h = sm + C::OFF_X;    unsigned short* Y2l = Y2h + R * C::SY2;

    {
        const int r = tid / TPR, s = tid % TPR;
        int pid;
        {
            const int cA = bqm[256 + 0], cB = bqm[256 + 1], cC = bqm[256 + 2], cD = bqm[256 + 3];
            const int tot = cA + cB + cC + cD;
            int t = half * R + r;
            if (t < tot) {
                int ww = 0;
                if (t >= cA) { t -= cA; ww = 1;
                    if (t >= cB) { t -= cB; ww = 2;
                        if (t >= cC) { t -= cC; ww = 3; } } }
                pid = bqm[ww * 64 + t];
            } else {
                const int fA = bqm[260 + 0], fB = bqm[260 + 1], fC = bqm[260 + 2], fD = bqm[260 + 3];
                pid = fA >= 0 ? fA : (fB >= 0 ? fB : (fC >= 0 ? fC : (fD >= 0 ? fD : (N - 1))));
            }
        }
        unsigned short* xh = Xhi + r * C::SX;
        unsigned short* xl = Xlo + r * C::SX;
        if constexpr (CF > 0) {
            constexpr int CPT = CF / TPR;
            const float* frow = src_feat + ((size_t)b * N + pid) * CF + s * CPT;
#pragma unroll
            for (int q = 0; q < CPT / 4; ++q) {
                float4 v4 = *reinterpret_cast<const float4*>(frow + q * 4);
                ushort4 h, l;
                h.x = f2bf(v4.x); l.x = f2bf(v4.x - bf2f(h.x));
                h.y = f2bf(v4.y); l.y = f2bf(v4.y - bf2f(h.y));
                h.z = f2bf(v4.z); l.z = f2bf(v4.z - bf2f(h.z));
                h.w = f2bf(v4.w); l.w = f2bf(v4.w - bf2f(h.w));
                *reinterpret_cast<ushort4*>(xh + s * CPT + q * 4) = h;
                *reinterpret_cast<ushort4*>(xl + s * CPT + q * 4) = l;
            }
        }
        if (s < 3) {
            float p = src_xyz[((size_t)b * N + pid) * 3 + s]
                      - (s == 0 ? cx : (s == 1 ? cy : cz));
            unsigned short hi = f2bf(p), lo = f2bf(p - bf2f(hi));
            xh[CF + s] = hi; xl[CF + s] = lo;
        }
        constexpr int PADPER = (C::KP0 - C::CIN + TPR - 1) / TPR;
#pragma unroll
        for (int q = 0; q < PADPER; ++q) {
            int c = C::CIN + s * PADPER + q;
            if (c < C::KP0) { xh[c] = 0; xl[c] = 0; }
        }
    }
    __syncthreads();
    mfma_layer<C::CIN, C0, 0, C0, C::RT, C::SX, C::SY1, false>(
        w0h, w0l, g0, b0, Xhi, Xlo, Y1h, Y1l, nullptr, tid);
    __syncthreads();
    mfma_layer<C0, C1, 0, C1, C::RT, C::SY1, C::SY2, false>(
        w1h, w1l, g1, b1, Y1h, Y1l, Y2h, Y2l, nullptr, tid);
    __syncthreads();
    mfma_layer<C1, C2, 0, C2, C::RT, C::SY2, 0, true>(
        w2h, w2l, g2, b2, Y2h, Y2l, nullptr, nullptr,
        out_feat + (size_t)bs * C2, tid);
}

// ============================= Kernels =============================
// K1: FPS1 part1 (256 centers) + weight prep + zero-fill (feat1, feat2, out, flags)
template<int N1>
__global__ __launch_bounds__(NTH) void k_fps1a_prep(
    const float* __restrict__ pc, float* __restrict__ nxyz1,
    const float* __restrict__ w0, const float* __restrict__ w1, const float* __restrict__ w2,
    const float* __restrict__ w3, const float* __restrict__ w4, const float* __restrict__ w5,
    const float* __restrict__ w6, const float* __restrict__ w7, const float* __restrict__ w8,
    unsigned short* __restrict__ outw,
    float* __restrict__ sdist, int* __restrict__ slast,
    float4* __restrict__ z1, int n1, float4* __restrict__ z2, int n2,
    float4* __restrict__ z3, int n3, float4* __restrict__ z4, int n4,
    int nfps, int nprep)
{
    __shared__ float pts[N1 * 3];
    __shared__ float ctr[256 * 3];
    __shared__ unsigned long long wkey[2 * (NTH / 64)];
    if ((int)blockIdx.x < nfps) {
        fps1a_body<N1, 512, NTH, 256>(pc, nxyz1, blockIdx.x, pts, ctr, wkey, sdist, slast);
    } else if ((int)blockIdx.x < nfps + nprep) {
        prep_body((blockIdx.x - nfps) * NTH + threadIdx.x, nprep * NTH,
                  w0, w1, w2, w3, w4, w5, w6, w7, w8, outw);
    } else {
        const int zid = (blockIdx.x - nfps - nprep) * NTH + threadIdx.x;
        const int zs  = (gridDim.x - nfps - nprep) * NTH;
        const float4 zv = make_float4(0.f, 0.f, 0.f, 0.f);
        for (int i = zid; i < n4; i += zs) z4[i] = zv;   // flags first
        for (int i = zid; i < n1; i += zs) z1[i] = zv;
        for (int i = zid; i < n2; i += zs) z2[i] = zv;
        for (int i = zid; i < n3; i += zs) z3[i] = zv;
    }
}

// K2: [FPS1 part2 (256 iters, 32-chunk flags) -> FPS2] (blocks 0..31) || SA1 ALL
__global__ __launch_bounds__(NTH) void k_fps1b2_sa1(
    const float* __restrict__ pc, float* __restrict__ nxyz1, float* __restrict__ nxyz2,
    const float* __restrict__ sdist, const int* __restrict__ slast,
    int* __restrict__ flags,
    const unsigned short* __restrict__ w0h, const unsigned short* __restrict__ w0l,
    const unsigned short* __restrict__ w1h, const unsigned short* __restrict__ w1l,
    const unsigned short* __restrict__ w2h, const unsigned short* __restrict__ w2l,
    const float* __restrict__ g0, const float* __restrict__ b0,
    const float* __restrict__ g1, const float* __restrict__ b1,
    const float* __restrict__ g2, const float* __restrict__ b2,
    float* __restrict__ feat1, float r2)
{
    constexpr int FPSB = 4096 * 3 * 4 + 256 * 3 * 4 + 2 * (NTH / 64) * 8;
    constexpr int SAB  = SaCfg<0, 64, 64, 128, 64>::BYTES;
    constexpr int BYTES = FPSB > SAB ? FPSB : SAB;
    __shared__ __align__(16) char raw[BYTES];
    if ((int)blockIdx.x < 32) {
        const int b = blockIdx.x;
        {
            float* pts = (float*)raw;
            float* ctr = (float*)(raw + 4096 * 3 * 4);
            unsigned long long* wkey = (unsigned long long*)(raw + 4096 * 3 * 4 + 256 * 3 * 4);
            fps1b_body<4096, NTH, 256, 256>(pc, nxyz1, b, pts, ctr, wkey, sdist, slast, flags);
        }
        __syncthreads();
        {
            float* pts = (float*)raw;
            float* ctr = (float*)(raw + 512 * 3 * 4);
            fps2_wave_body<512, 128>(nxyz1, nxyz2, b, pts, ctr);
        }
    } else {
        // grid ordered by 32-center group: groups 0..7 (cs<256) dispatch first, no wait
        const int blk = blockIdx.x - 32;
        const int g = blk / (32 * 32);
        const int o = blk % (32 * 32);
        const int b = o >> 5;
        const int cs = g * 32 + (o & 31);
        if (cs >= 256) {
            if (threadIdx.x == 0) {
                while (__hip_atomic_load(&flags[b * 8 + ((cs >> 5) - 8)],
                                         __ATOMIC_ACQUIRE, __HIP_MEMORY_SCOPE_AGENT) == 0)
                    __builtin_amdgcn_s_sleep(16);
            }
            __syncthreads();
        }
        unsigned short* sm = (unsigned short*)raw;
        int* bqm = (int*)(raw + SaCfg<0, 64, 64, 128, 64>::TOT * 2);
        sa_body<0, 64, 64, 128, 64>(sm, bqm, b, cs, 512, 0,
                                    pc, nullptr, nxyz1,
                                    w0h, w0l, w1h, w1l, w2h, w2l,
                                    g0, b0, g1, b1, g2, b2, feat1, 4096, r2);
    }
}

// K3: SA2 (fused bq, 2 halves per center — R12 config)
__global__ __launch_bounds__(NTH) void k_sa2(
    const float* __restrict__ nxyz1, const float* __restrict__ feat1,
    const float* __restrict__ nxyz2,
    const unsigned short* __restrict__ w0h, const unsigned short* __restrict__ w0l,
    const unsigned short* __restrict__ w1h, const unsigned short* __restrict__ w1l,
    const unsigned short* __restrict__ w2h, const unsigned short* __restrict__ w2l,
    const float* __restrict__ g0, const float* __restrict__ b0,
    const float* __restrict__ g1, const float* __restrict__ b1,
    const float* __restrict__ g2, const float* __restrict__ b2,
    float* __restrict__ feat2, float r2)
{
    using C = SaCfg<128, 128, 128, 256, 32>;
    __shared__ __align__(16) char raw[C::BYTES];
    const int half = blockIdx.x & 1;
    const int cb   = blockIdx.x >> 1;
    const int b = cb >> 7, cs = cb & 127;
    unsigned short* sm = (unsigned short*)raw;
    int* bqm = (int*)(raw + C::TOT * 2);
    sa_body<128, 128, 128, 256, 32>(sm, bqm, b, cs, 128, half,
                                    nxyz1, feat1, nxyz2,
                                    w0h, w0l, w1h, w1l, w2h, w2l,
                                    g0, b0, g1, b1, g2, b2, feat2, 512, r2);
}

// ===================== Head (unchanged) =====================
template<int CF, int C0, int C1, int C2>
__global__ __launch_bounds__(NTH) void head_mfma(
    const float* __restrict__ xyz, const float* __restrict__ feat,
    const unsigned short* __restrict__ w0h, const unsigned short* __restrict__ w0l,
    const unsigned short* __restrict__ w1h, const unsigned short* __restrict__ w1l,
    const unsigned short* __restrict__ w2h, const unsigned short* __restrict__ w2l,
    const float* __restrict__ g0, const float* __restrict__ b0,
    const float* __restrict__ g1, const float* __restrict__ b1,
    const float* __restrict__ g2, const float* __restrict__ b2,
    float* __restrict__ out, int Np)
{
    constexpr int R = 16;
    constexpr int CIN = 3 + CF;
    constexpr int KP0 = (CIN + 31) & ~31;
    constexpr int SX = KP0 + 8, SY1 = C0 + 8, SY2 = C1 + 8;
    constexpr int OFF_Y1 = 0;
    constexpr int OFF_X  = 2 * R * SY1;
    constexpr int XSZ = 2 * R * SX, Y2SZ = 2 * R * SY2;
    constexpr int TOT = OFF_X + (XSZ > Y2SZ ? XSZ : Y2SZ);
    __shared__ __align__(16) unsigned short sm[TOT];
    constexpr int TPR = NTH / R;

    const int tid = threadIdx.x;
    const int chunks = Np / R;
    const int b  = blockIdx.x / chunks;
    const int r0 = (blockIdx.x % chunks) * R;

    unsigned short* Xhi = sm + OFF_X;   unsigned short* Xlo = Xhi + R * SX;
    unsigned short* Y1h = sm + OFF_Y1;  unsigned short* Y1l = Y1h + R * SY1;
    unsigned short* Y2h = sm + OFF_X;   unsigned short* Y2l = Y2h + R * SY2;

    {
        const int r = tid / TPR, s = tid % TPR;
        const int row = r0 + r;
        unsigned short* xh = Xhi + r * SX;
        unsigned short* xl = Xlo + r * SX;
        constexpr int CPT = CF / TPR;
        const float* frow = feat + ((size_t)b * Np + row) * CF + s * CPT;
#pragma unroll
        for (int q = 0; q < CPT / 4; ++q) {
            float4 v4 = *reinterpret_cast<const float4*>(frow + q * 4);
            ushort4 h, l;
            h.x = f2bf(v4.x); l.x = f2bf(v4.x - bf2f(h.x));
            h.y = f2bf(v4.y); l.y = f2bf(v4.y - bf2f(h.y));
            h.z = f2bf(v4.z); l.z = f2bf(v4.z - bf2f(h.z));
            h.w = f2bf(v4.w); l.w = f2bf(v4.w - bf2f(h.w));
            *reinterpret_cast<ushort4*>(xh + s * CPT + q * 4) = h;
            *reinterpret_cast<ushort4*>(xl + s * CPT + q * 4) = l;
        }
        if (s < 3) {
            float p = xyz[((size_t)b * Np + row) * 3 + s];
            unsigned short hi = f2bf(p), lo = f2bf(p - bf2f(hi));
            xh[CF + s] = hi; xl[CF + s] = lo;
        }
        constexpr int PADPER = (KP0 - CIN + TPR - 1) / TPR;
#pragma unroll
        for (int q = 0; q < PADPER; ++q) {
            int c = CIN + s * PADPER + q;
            if (c < KP0) { xh[c] = 0; xl[c] = 0; }
        }
    }
    __syncthreads();
    mfma_layer<CIN, C0, 0, C0, 1, SX, SY1, false>(w0h, w0l, g0, b0, Xhi, Xlo, Y1h, Y1l, nullptr, tid);
    __syncthreads();
    mfma_layer<C0, C1, 0, C1, 1, SY1, SY2, false>(w1h, w1l, g1, b1, Y1h, Y1l, Y2h, Y2l, nullptr, tid);
    __syncthreads();
    float* op = out + (size_t)b * C2;
    mfma_layer<C1, C2 / 2, 0,      C2, 1, SY2, 0, true>(w2h, w2l, g2, b2, Y2h, Y2l, nullptr, nullptr, op, tid);
    mfma_layer<C1, C2 / 2, C2 / 2, C2, 1, SY2, 0, true>(w2h, w2l, g2, b2, Y2h, Y2l, nullptr, nullptr, op, tid);
}

// ============================== launch ==============================
extern "C" void kernel_launch(void* const* d_in, const int* in_sizes, int n_in,
                              void* d_out, int out_size, void* d_ws, size_t ws_size,
                              hipStream_t stream)
{
    (void)in_sizes; (void)n_in; (void)ws_size;
    const int B = 32;
    const float* pc = (const float*)d_in[0];
    const float* W[27];
    for (int i = 0; i < 27; ++i) W[i] = (const float*)d_in[1 + i];
    float* out = (float*)d_out;

    char* ws = (char*)d_ws;
    size_t off = 0;
    auto take = [&](size_t bytes) {
        void* p = ws + off;
        off += (bytes + 255) & ~(size_t)255;
        return p;
    };
    float* nxyz1 = (float*)take((size_t)B * 512 * 3 * 4);
    float* feat1 = (float*)take((size_t)B * 512 * 128 * 4);
    float* nxyz2 = (float*)take((size_t)B * 128 * 3 * 4);
    float* feat2 = (float*)take((size_t)B * 128 * 256 * 4);
    unsigned short* wf = (unsigned short*)take((size_t)1626112 * 2);
    float* sdist = (float*)take((size_t)B * 4096 * 4);
    int*   slast = (int*)take((size_t)B * 4);
    int*   flags = (int*)take((size_t)B * 8 * 4);   // [B][8] 32-center chunk flags

    const int E_[9]    = {2048, 4096, 8192, 20480, 16384, 32768, 73728, 131072, 524288};
    const int base_[9] = {0, 4096, 12288, 28672, 69632, 102400, 167936, 315392, 577536};
    const unsigned short* wh[9]; const unsigned short* wl[9];
    for (int i = 0; i < 9; ++i) { wh[i] = wf + base_[i]; wl[i] = wf + base_[i] + E_[i]; }

    const float r2_1 = (float)(0.2 * 0.2);
    const float r2_2 = (float)(0.4 * 0.4);

    // K1: FPS1 part1 (256) + weight prep + zero-fill
    k_fps1a_prep<4096><<<32 + 512 + 64, NTH, 0, stream>>>(
        pc, nxyz1,
        W[0], W[3], W[6], W[9], W[12], W[15], W[18], W[21], W[24],
        wf, sdist, slast,
        (float4*)feat1, B * 512 * 128 / 4,
        (float4*)feat2, B * 128 * 256 / 4,
        (float4*)out,   out_size / 4,
        (float4*)flags, B * 8 * 4 / 16,
        32, 512);

    // K2: [FPS1 part2 (256) -> FPS2] || SA1 all (32-chunk flag consumers)
    k_fps1b2_sa1<<<32 + B * 512, NTH, 0, stream>>>(
        pc, nxyz1, nxyz2, sdist, slast, flags,
        wh[0], wl[0], wh[1], wl[1], wh[2], wl[2],
        W[1], W[2], W[4], W[5], W[7], W[8],
        feat1, r2_1);

    // K3: SA2
    k_sa2<<<B * 128 * 2, NTH, 0, stream>>>(
        nxyz1, feat1, nxyz2,
        wh[3], wl[3], wh[4], wl[4], wh[5], wl[5],
        W[10], W[11], W[13], W[14], W[16], W[17],
        feat2, r2_2);

    // K4: head
    head_mfma<256, 256, 512, 1024><<<B * 8, NTH, 0, stream>>>(
        nxyz2, feat2,
        wh[6], wl[6], wh[7], wl[7], wh[8], wl[8],
        W[19], W[20], W[22], W[23], W[25], W[26],
        out, 128);
}